// Round 1
// baseline (875.136 us; speedup 1.0000x reference)
//
#include <hip/hip_runtime.h>
#include <math.h>

#define NROWS 16      // batch rows per block
#define DD    256     // input dim
#define HH    512     // hidden dim
#define NJ    24      // joints
#define OUTC  92      // (NJ-1)*4

__constant__ int c_parent[NJ] = {-1,0,0,0,1,2,3,4,5,6,7,8,9,9,9,12,13,14,16,17,18,19,20,21};

__global__ __launch_bounds__(256)
void fused_skel_f32(const float* __restrict__ z, const float* __restrict__ W1,
                    const float* __restrict__ b1, const float* __restrict__ W2,
                    const float* __restrict__ b2, float* __restrict__ out, long Btot)
{
    __shared__ float h_s[NROWS][HH];        // 32 KB
    __shared__ float raw_s[NROWS][96];      // 6 KB (pad 92->96)
    __shared__ float offs_s[NROWS][NJ * 3]; // 4.5 KB

    const int tid = threadIdx.x;
    const long r0 = (long)blockIdx.x * NROWS;

    float* joints  = out;
    float* offsets = out + Btot * (NJ * 3);
    float* length  = out + 2 * Btot * (NJ * 3);

    // ---------------- GEMM1: h = silu(z @ W1 + b1) ----------------
    // thread handles one column c for all 16 rows; two column halves.
    #pragma unroll 1
    for (int hf = 0; hf < 2; ++hf) {
        const int c = tid + (hf << 8);
        float acc[NROWS];
        #pragma unroll
        for (int r = 0; r < NROWS; ++r) acc[r] = 0.f;

        #pragma unroll 1
        for (int k = 0; k < DD; k += 4) {
            // coalesced across lanes (consecutive c), L2-resident W1
            const float w0 = W1[(k + 0) * HH + c];
            const float w1v = W1[(k + 1) * HH + c];
            const float w2v = W1[(k + 2) * HH + c];
            const float w3v = W1[(k + 3) * HH + c];
            #pragma unroll
            for (int r = 0; r < NROWS; ++r) {
                // wave-uniform address -> scalar load path
                const float4 zv = *reinterpret_cast<const float4*>(z + (r0 + r) * DD + k);
                acc[r] = fmaf(zv.x, w0, acc[r]);
                acc[r] = fmaf(zv.y, w1v, acc[r]);
                acc[r] = fmaf(zv.z, w2v, acc[r]);
                acc[r] = fmaf(zv.w, w3v, acc[r]);
            }
        }
        const float bb = b1[c];
        #pragma unroll
        for (int r = 0; r < NROWS; ++r) {
            const float a = acc[r] + bb;
            h_s[r][c] = a / (1.f + expf(-a));   // silu
        }
    }
    __syncthreads();

    // ---------------- GEMM2: raw = h @ W2 + b2 ----------------
    // 192 active threads: c2 = tid%96 (compute c2<92), row group rg = tid/96 (8 rows each)
    {
        const int c2 = tid % 96;
        const int rg = tid / 96;
        if (rg < 2 && c2 < OUTC) {
            float acc2[8];
            #pragma unroll
            for (int rr = 0; rr < 8; ++rr) acc2[rr] = 0.f;
            #pragma unroll 1
            for (int k = 0; k < HH; k += 4) {
                const float w0 = W2[(k + 0) * OUTC + c2];
                const float w1v = W2[(k + 1) * OUTC + c2];
                const float w2v = W2[(k + 2) * OUTC + c2];
                const float w3v = W2[(k + 3) * OUTC + c2];
                #pragma unroll
                for (int rr = 0; rr < 8; ++rr) {
                    const float4 hv = *reinterpret_cast<const float4*>(&h_s[rg * 8 + rr][k]);
                    acc2[rr] = fmaf(hv.x, w0, acc2[rr]);
                    acc2[rr] = fmaf(hv.y, w1v, acc2[rr]);
                    acc2[rr] = fmaf(hv.z, w2v, acc2[rr]);
                    acc2[rr] = fmaf(hv.w, w3v, acc2[rr]);
                }
            }
            const float bb2 = b2[c2];
            #pragma unroll
            for (int rr = 0; rr < 8; ++rr) raw_s[rg * 8 + rr][c2] = acc2[rr] + bb2;
        }
    }
    __syncthreads();

    // ---------------- epilogue: normalize / softplus / offsets ----------------
    for (int task = tid; task < NROWS * (NJ - 1); task += 256) {
        const int r = task / (NJ - 1);
        const int j = task % (NJ - 1);          // non-root joint index, joint id j+1
        const float x  = raw_s[r][4 * j + 0];
        const float y  = raw_s[r][4 * j + 1];
        const float zz = raw_s[r][4 * j + 2];
        const float lr = raw_s[r][4 * j + 3];
        const float nrm = sqrtf(x * x + y * y + zz * zz);
        const float inv = 1.f / fmaxf(nrm, 1e-6f);
        // stable softplus: max(x,0) + log1p(exp(-|x|))
        const float len = fmaxf(lr, 0.f) + log1pf(expf(-fabsf(lr)));
        offs_s[r][3 * (j + 1) + 0] = x * inv * len;
        offs_s[r][3 * (j + 1) + 1] = y * inv * len;
        offs_s[r][3 * (j + 1) + 2] = zz * inv * len;
        length[(r0 + r) * (NJ - 1) + j] = len;
    }
    // zero the root offset
    for (int task = tid; task < NROWS * 3; task += 256)
        offs_s[task / 3][task % 3] = 0.f;
    __syncthreads();

    // ---------------- joints: ancestor-chain sums + output writes ----------------
    for (int task = tid; task < NROWS * NJ; task += 256) {
        const int r = task / NJ;
        const int j = task % NJ;
        float jx = 0.f, jy = 0.f, jz = 0.f;
        int k = j;
        while (k > 0) {
            jx += offs_s[r][3 * k + 0];
            jy += offs_s[r][3 * k + 1];
            jz += offs_s[r][3 * k + 2];
            k = c_parent[k];
        }
        const long base = (r0 + r) * (NJ * 3) + j * 3;
        joints[base + 0] = jx;
        joints[base + 1] = jy;
        joints[base + 2] = jz;
    }
    // offsets output (contiguous per row-tile -> fully coalesced)
    for (int idx = tid; idx < NROWS * NJ * 3; idx += 256) {
        const int r = idx / (NJ * 3);
        const int rem = idx % (NJ * 3);
        offsets[(r0 + r) * (NJ * 3) + rem] = offs_s[r][rem];
    }
}

extern "C" void kernel_launch(void* const* d_in, const int* in_sizes, int n_in,
                              void* d_out, int out_size, void* d_ws, size_t ws_size,
                              hipStream_t stream) {
    const float* z  = (const float*)d_in[0];
    const float* W1 = (const float*)d_in[1];
    const float* b1 = (const float*)d_in[2];
    const float* W2 = (const float*)d_in[3];
    const float* b2 = (const float*)d_in[4];
    float* out = (float*)d_out;

    const long Btot = (long)in_sizes[0] / DD;   // 131072
    const int blocks = (int)(Btot / NROWS);     // 8192

    fused_skel_f32<<<blocks, 256, 0, stream>>>(z, W1, b1, W2, b2, out, Btot);
}

// Round 2
// 247.688 us; speedup vs baseline: 3.5332x; 3.5332x over previous
//
#include <hip/hip_runtime.h>
#include <math.h>

typedef _Float16 half8 __attribute__((ext_vector_type(8)));
typedef float floatx4 __attribute__((ext_vector_type(4)));

#define DD 256
#define HH 512
#define OC 92
#define NJ 24
#define BM 64
#define NCHUNK 16   // 512 / 32
// ws layout in halfs:
#define W1L_OFF 131072
#define W2H_OFF 262144
#define W2L_OFF 311296
// total ws need: 360448 halfs = 720896 bytes

__constant__ int c_parent[NJ] = {-1,0,0,0,1,2,3,4,5,6,7,8,9,9,9,12,13,14,16,17,18,19,20,21};

// ---- fragment maps (single source of truth) ----
// A-frag (MxK=16x32): lane l holds row=l&15, k = 4*(l>>4) + (j&3) + 16*(j>>2), j=0..7
// B-frag (KxN=32x16): lane l holds col=l&15, k = same formula
// C/D   (16x16):      reg i: row = 4*(l>>4)+i, col = l&15   [m89-verified]

__global__ __launch_bounds__(256)
void presplit_w1(const float* __restrict__ W1, _Float16* __restrict__ ws) {
    int idx = blockIdx.x * 256 + threadIdx.x;      // 0..131071
    int k = idx >> 9;                              // row 0..255
    int c = idx & 511;                             // col 0..511
    float v = W1[idx];
    _Float16 hi = (_Float16)v;
    _Float16 lo = (_Float16)((v - (float)hi) * 2048.0f);
    int ckI   = c >> 5;
    int cfrag = (c >> 4) & 1;
    int lane  = (((k & 15) >> 2) << 4) | (c & 15);
    int j     = (k & 3) | (((k >> 4) & 1) << 2);
    int ks    = k >> 5;
    int addr  = (((ckI * 8 + ks) * 2 + cfrag) * 64 + lane) * 8 + j;
    ws[addr] = hi;
    ws[W1L_OFF + addr] = lo;
}

__global__ __launch_bounds__(256)
void presplit_w2(const float* __restrict__ W2, _Float16* __restrict__ ws) {
    int idx = blockIdx.x * 256 + threadIdx.x;      // 0..49151
    int k = idx / 96;                              // 0..511
    int c = idx - k * 96;                          // 0..95
    float v = (c < OC) ? W2[k * OC + c] : 0.0f;
    _Float16 hi = (_Float16)v;
    _Float16 lo = (_Float16)((v - (float)hi) * 2048.0f);
    int ckI   = k >> 5;
    int cfrag = c >> 4;
    int lane  = (((k & 15) >> 2) << 4) | (c & 15);
    int j     = (k & 3) | (((k >> 4) & 1) << 2);
    int addr  = ((ckI * 6 + cfrag) * 64 + lane) * 8 + j;
    ws[W2H_OFF + addr] = hi;
    ws[W2L_OFF + addr] = lo;
}

__global__ __launch_bounds__(256)
void fused_main(const float* __restrict__ z, const _Float16* __restrict__ wsp,
                const float* __restrict__ b1, const float* __restrict__ b2,
                float* __restrict__ out, long long Btot)
{
    __shared__ __align__(16) char smem[55680];
    _Float16* s_w1h = (_Float16*)(smem);            // 8192 halfs (16 KB)
    _Float16* s_w1l = (_Float16*)(smem + 16384);
    _Float16* s_w2h = (_Float16*)(smem + 32768);    // 3072 halfs (6 KB)
    _Float16* s_w2l = (_Float16*)(smem + 38912);
    _Float16* s_hh  = (_Float16*)(smem + 45056);    // 2048 halfs (4 KB)
    _Float16* s_hl  = (_Float16*)(smem + 49152);
    float*    s_b1  = (float*)(smem + 53248);       // 512 f32
    float*    s_b2  = (float*)(smem + 55296);       // 96 f32
    float*    s_raw = (float*)(smem);               // phase B: [64][96] f32
    float*    s_off = (float*)(smem + 24576);       // phase B: [64][72] f32

    const int tid = threadIdx.x;
    const int w   = tid >> 6;
    const int l   = tid & 63;
    const int l15 = l & 15;
    const int l4  = l >> 4;
    const long long R0 = (long long)blockIdx.x * BM;

    // stage biases (visible after first in-loop barrier)
    s_b1[tid]       = b1[tid];
    s_b1[tid + 256] = b1[tid + 256];
    if (tid < 96) s_b2[tid] = (tid < OC) ? b2[tid] : 0.0f;

    // ---- preload z A-fragments (hi/lo) for this wave's 16 rows ----
    half8 zh[8], zl[8];
    {
        const float* zrow = z + (R0 + (long long)(w * 16 + l15)) * DD;
        #pragma unroll
        for (int ks = 0; ks < 8; ++ks) {
            const float* p = zrow + ks * 32 + l4 * 4;
            float4 va = *(const float4*)p;
            float4 vb = *(const float4*)(p + 16);
            half8 th, tl;
            #define CVTZ(J, V) { _Float16 t_ = (_Float16)(V); th[J] = t_; tl[J] = (_Float16)(((V) - (float)t_) * 2048.0f); }
            CVTZ(0, va.x) CVTZ(1, va.y) CVTZ(2, va.z) CVTZ(3, va.w)
            CVTZ(4, vb.x) CVTZ(5, vb.y) CVTZ(6, vb.z) CVTZ(7, vb.w)
            #undef CVTZ
            zh[ks] = th; zl[ks] = tl;
        }
    }

    floatx4 a2m[6], a2c[6];
    #pragma unroll
    for (int i = 0; i < 6; ++i) { a2m[i] = (floatx4)0.0f; a2c[i] = (floatx4)0.0f; }

    #pragma unroll 1
    for (int ck = 0; ck < NCHUNK; ++ck) {
        // ---- stage pre-split W1 chunk (32 KB) + W2 chunk (12 KB), linear copies ----
        {
            const _Float16* g1h = wsp + ck * 8192;
            const _Float16* g1l = wsp + W1L_OFF + ck * 8192;
            #pragma unroll
            for (int r = 0; r < 4; ++r) {
                int idx = r * 256 + tid;
                *(float4*)(s_w1h + idx * 8) = *(const float4*)(g1h + idx * 8);
                *(float4*)(s_w1l + idx * 8) = *(const float4*)(g1l + idx * 8);
            }
            const _Float16* g2h = wsp + W2H_OFF + ck * 3072;
            const _Float16* g2l = wsp + W2L_OFF + ck * 3072;
            *(float4*)(s_w2h + tid * 8) = *(const float4*)(g2h + tid * 8);
            *(float4*)(s_w2l + tid * 8) = *(const float4*)(g2l + tid * 8);
            int idx2 = 256 + tid;
            if (idx2 < 384) {
                *(float4*)(s_w2h + idx2 * 8) = *(const float4*)(g2h + idx2 * 8);
                *(float4*)(s_w2l + idx2 * 8) = *(const float4*)(g2l + idx2 * 8);
            }
        }
        __syncthreads();   // B1: staging visible

        // ---- GEMM1: this wave's 16 rows x 32 chunk-cols, K=256 ----
        floatx4 am[2], ac[2];
        am[0] = (floatx4)0.0f; am[1] = (floatx4)0.0f;
        ac[0] = (floatx4)0.0f; ac[1] = (floatx4)0.0f;
        #pragma unroll
        for (int ks = 0; ks < 8; ++ks) {
            #pragma unroll
            for (int cf = 0; cf < 2; ++cf) {
                half8 bh = *(half8*)(s_w1h + ((ks * 2 + cf) * 64 + l) * 8);
                half8 bl = *(half8*)(s_w1l + ((ks * 2 + cf) * 64 + l) * 8);
                am[cf] = __builtin_amdgcn_mfma_f32_16x16x32_f16(zh[ks], bh, am[cf], 0, 0, 0);
                ac[cf] = __builtin_amdgcn_mfma_f32_16x16x32_f16(zh[ks], bl, ac[cf], 0, 0, 0);
                ac[cf] = __builtin_amdgcn_mfma_f32_16x16x32_f16(zl[ks], bh, ac[cf], 0, 0, 0);
            }
        }

        // ---- h = silu(.) ; re-split to hi/lo ; wave-private C->A layout bounce ----
        #pragma unroll
        for (int cf = 0; cf < 2; ++cf) {
            #pragma unroll
            for (int i = 0; i < 4; ++i) {
                float a = am[cf][i] + ac[cf][i] * (1.0f / 2048.0f) + s_b1[ck * 32 + cf * 16 + l15];
                float hv = a / (1.0f + expf(-a));
                _Float16 th = (_Float16)hv;
                _Float16 tl = (_Float16)((hv - (float)th) * 2048.0f);
                int row   = l4 * 4 + i;                       // 0..15
                int lane2 = ((l15 >> 2) << 4) | row;
                int j2    = (l15 & 3) | (cf << 2);
                int ad    = (w * 64 + lane2) * 8 + j2;
                s_hh[ad] = th;
                s_hl[ad] = tl;
            }
        }

        // ---- GEMM2 partial: K-slice = this chunk's 32 h-cols (wave-private A) ----
        {
            half8 ah = *(half8*)(s_hh + (w * 64 + l) * 8);
            half8 al = *(half8*)(s_hl + (w * 64 + l) * 8);
            #pragma unroll
            for (int cf = 0; cf < 6; ++cf) {
                half8 bh = *(half8*)(s_w2h + (cf * 64 + l) * 8);
                half8 bl = *(half8*)(s_w2l + (cf * 64 + l) * 8);
                a2m[cf] = __builtin_amdgcn_mfma_f32_16x16x32_f16(ah, bh, a2m[cf], 0, 0, 0);
                a2c[cf] = __builtin_amdgcn_mfma_f32_16x16x32_f16(ah, bl, a2c[cf], 0, 0, 0);
                a2c[cf] = __builtin_amdgcn_mfma_f32_16x16x32_f16(al, bh, a2c[cf], 0, 0, 0);
            }
        }
        __syncthreads();   // B2: all reads done before next stage overwrites
    }

    // ---- write raw logits to LDS (aliases W1 region; safe after last B2) ----
    #pragma unroll
    for (int cf = 0; cf < 6; ++cf) {
        #pragma unroll
        for (int i = 0; i < 4; ++i) {
            int c = cf * 16 + l15;
            if (c < OC) {
                int r = w * 16 + l4 * 4 + i;
                s_raw[r * 96 + c] = a2m[cf][i] + a2c[cf][i] * (1.0f / 2048.0f) + s_b2[c];
            }
        }
    }
    __syncthreads();

    float* joints  = out;
    float* offsets = out + Btot * (NJ * 3);
    float* length  = out + 2 * Btot * (NJ * 3);

    // ---- epilogue: normalize / softplus / offsets (verified in R1) ----
    for (int task = tid; task < BM * (NJ - 1); task += 256) {
        int r = task / (NJ - 1);
        int j = task - r * (NJ - 1);
        float x  = s_raw[r * 96 + 4 * j + 0];
        float y  = s_raw[r * 96 + 4 * j + 1];
        float zz = s_raw[r * 96 + 4 * j + 2];
        float lr = s_raw[r * 96 + 4 * j + 3];
        float nrm = sqrtf(x * x + y * y + zz * zz);
        float inv = 1.0f / fmaxf(nrm, 1e-6f);
        float len = fmaxf(lr, 0.0f) + log1pf(expf(-fabsf(lr)));
        s_off[r * 72 + 3 * (j + 1) + 0] = x * inv * len;
        s_off[r * 72 + 3 * (j + 1) + 1] = y * inv * len;
        s_off[r * 72 + 3 * (j + 1) + 2] = zz * inv * len;
        length[(R0 + r) * (NJ - 1) + j] = len;
    }
    for (int t2 = tid; t2 < BM * 3; t2 += 256)
        s_off[(t2 / 3) * 72 + (t2 % 3)] = 0.0f;
    __syncthreads();

    // ---- joints: ancestor-chain sums + coalesced output writes ----
    for (int task = tid; task < BM * NJ; task += 256) {
        int r = task / NJ;
        int j = task - r * NJ;
        float jx = 0.0f, jy = 0.0f, jz = 0.0f;
        int k = j;
        while (k > 0) {
            jx += s_off[r * 72 + 3 * k + 0];
            jy += s_off[r * 72 + 3 * k + 1];
            jz += s_off[r * 72 + 3 * k + 2];
            k = c_parent[k];
        }
        long long base = (R0 + r) * (NJ * 3) + j * 3;
        joints[base + 0] = jx;
        joints[base + 1] = jy;
        joints[base + 2] = jz;
    }
    for (int idx = tid; idx < BM * NJ * 3; idx += 256) {
        int r = idx / (NJ * 3);
        int rem = idx - r * (NJ * 3);
        offsets[(R0 + r) * (NJ * 3) + rem] = s_off[r * 72 + rem];
    }
}

extern "C" void kernel_launch(void* const* d_in, const int* in_sizes, int n_in,
                              void* d_out, int out_size, void* d_ws, size_t ws_size,
                              hipStream_t stream) {
    const float* z  = (const float*)d_in[0];
    const float* W1 = (const float*)d_in[1];
    const float* b1 = (const float*)d_in[2];
    const float* W2 = (const float*)d_in[3];
    const float* b2 = (const float*)d_in[4];
    float* out = (float*)d_out;
    _Float16* ws = (_Float16*)d_ws;

    const long long Btot = (long long)in_sizes[0] / DD;   // 131072

    presplit_w1<<<512, 256, 0, stream>>>(W1, ws);
    presplit_w2<<<192, 256, 0, stream>>>(W2, ws);
    fused_main<<<(int)(Btot / BM), 256, 0, stream>>>(z, ws, b1, b2, out, Btot);
}